// Round 7
// baseline (166.764 us; speedup 1.0000x reference)
//
#include <hip/hip_runtime.h>

typedef __bf16 bf16x8 __attribute__((ext_vector_type(8)));
typedef float f32x4 __attribute__((ext_vector_type(4)));
typedef unsigned short u16x8 __attribute__((ext_vector_type(8)));

typedef const void __attribute__((address_space(1)))* gas_ptr;
typedef void __attribute__((address_space(3)))* las_ptr;

#define GLOAD16(gp, lp) __builtin_amdgcn_global_load_lds((gas_ptr)(gp), (las_ptr)(lp), 16, 0, 0)

__device__ __forceinline__ unsigned short f2bf(float f) {
  unsigned int u = __float_as_uint(f);
  u += 0x7FFF + ((u >> 16) & 1);
  return (unsigned short)(u >> 16);
}
__device__ __forceinline__ float bf2f(unsigned short u) {
  return __uint_as_float(((unsigned int)u) << 16);
}

// ---------------- merged prep: (by<8) W2 transpose->bf16 ; (by==8) mask+Hb+Astack ----------------
__global__ __launch_bounds__(256) void k_prep2(const float* __restrict__ W2,
                                               unsigned short* __restrict__ W2T,
                                               const float* __restrict__ z,
                                               const float* __restrict__ W1,
                                               const float* __restrict__ b1,
                                               unsigned short* __restrict__ Hb,
                                               unsigned short* __restrict__ Astack) {
  __shared__ float tile[64][65];
  const int t = threadIdx.x;
  if (blockIdx.y < 8) {
    const int gt = blockIdx.x;   // 64 tiles of 64 genes
    const int jt = blockIdx.y;   // 8 tiles of 64 j
    const int c = t & 63, r4 = t >> 6;
#pragma unroll
    for (int r = 0; r < 16; ++r) {
      int jj = r * 4 + r4;
      int g = gt * 64 + c;
      tile[jj][c] = (g < 4000) ? W2[(size_t)(jt * 64 + jj) * 4000 + g] : 0.f;
    }
    __syncthreads();
#pragma unroll
    for (int r = 0; r < 16; ++r) {
      int gg = r * 4 + r4;
      W2T[(size_t)(gt * 64 + gg) * 512 + jt * 64 + c] = f2bf(tile[c][gg]);
    }
  } else {
    float* zs = &tile[0][0];                       // 32 floats
    unsigned char* mk = (unsigned char*)&tile[2][0];  // 512 bytes
    for (int s = 0; s < 4; ++s) {
      int b = blockIdx.x * 4 + s;
      __syncthreads();
      if (t < 32) zs[t] = z[b * 32 + t];
      __syncthreads();
#pragma unroll
      for (int jj = 0; jj < 2; ++jj) {
        int j = t + jj * 256;
        float a = b1[j];
#pragma unroll
        for (int i = 0; i < 32; ++i) a = fmaf(zs[i], W1[i * 512 + j], a);
        bool m = a > 0.f;
        mk[j] = m ? 1 : 0;
        Hb[b * 512 + j] = m ? f2bf(a) : (unsigned short)0;
      }
      __syncthreads();
#pragma unroll
      for (int k = 0; k < 8; ++k) {
        int c8 = t + k * 256;      // 0..2047
        int row = c8 >> 6;         // 0..31
        int k8 = (c8 & 63) * 8;    // 0..504
        unsigned long long m8 = *(const unsigned long long*)(mk + k8);
        const float* w = W1 + row * 512 + k8;
        u16x8 out;
#pragma unroll
        for (int e = 0; e < 8; ++e)
          out[e] = ((m8 >> (e * 8)) & 0xffULL) ? f2bf(w[e]) : (unsigned short)0;
        *(u16x8*)(Astack + ((size_t)(b * 32 + row)) * 512 + k8) = out;
      }
    }
  }
}

// ---------------- k_s3: S = H @ W2T^T + b2 -> Cw ; coalesced LDS staging ----------
__global__ __launch_bounds__(256) void k_s3(const unsigned short* __restrict__ Hb,
                                            const unsigned short* __restrict__ W2T,
                                            const float* __restrict__ b2,
                                            const float* __restrict__ log_theta,
                                            float* __restrict__ Cw) {
  __shared__ __align__(16) char smem[24576];
  char* Abuf = smem;            // 2 * 4096
  char* Bbuf = smem + 8192;     // 2 * 8192

  const int bm = blockIdx.x;
  const int g0 = blockIdx.y * 64;
  const int t = threadIdx.x;
  const int lane = t & 63;
  const int wave = t >> 6;
  const int l8 = lane >> 3;
  const int kxor = (((lane & 7) ^ l8) << 3);
  const int c16 = lane & 15;
  const int lg = lane >> 4;

  f32x4 acc[2];
  acc[0] = (f32x4){0.f, 0.f, 0.f, 0.f};
  acc[1] = (f32x4){0.f, 0.f, 0.f, 0.f};

#define STAGE_S3(buf, kt)                                                             \
  do {                                                                                \
    GLOAD16(Hb + (size_t)(bm * 32 + wave * 8 + l8) * 512 + (kt) * 64 + kxor,          \
            Abuf + (buf) * 4096 + wave * 1024);                                       \
    _Pragma("unroll") for (int qq = 0; qq < 2; ++qq) {                                \
      int q = wave * 2 + qq;                                                          \
      GLOAD16(W2T + (size_t)(g0 + q * 8 + l8) * 512 + (kt) * 64 + kxor,               \
              Bbuf + (buf) * 8192 + q * 1024);                                        \
    }                                                                                 \
  } while (0)

  STAGE_S3(0, 0);
  __syncthreads();

  for (int kt = 0; kt < 8; ++kt) {
    int cur = kt & 1;
    if (kt < 7) STAGE_S3(cur ^ 1, kt + 1);
    const char* Ab = Abuf + cur * 4096;
    const char* Bb = Bbuf + cur * 8192;
#pragma unroll
    for (int ks = 0; ks < 2; ++ks) {
      int kb = ks * 64 + lg * 16;
      bf16x8 av[2], bv;
#pragma unroll
      for (int mt = 0; mt < 2; ++mt) {
        int row = mt * 16 + c16;
        av[mt] = *(const bf16x8*)(Ab + (row >> 3) * 1024 + (row & 7) * 128 + (kb ^ ((row & 7) << 4)));
      }
      {
        int row = wave * 16 + c16;
        bv = *(const bf16x8*)(Bb + (row >> 3) * 1024 + (row & 7) * 128 + (kb ^ ((row & 7) << 4)));
      }
#pragma unroll
      for (int mt = 0; mt < 2; ++mt)
        acc[mt] = __builtin_amdgcn_mfma_f32_16x16x32_bf16(av[mt], bv, acc[mt], 0, 0, 0);
    }
    __syncthreads();
  }

  {
    int g = g0 + wave * 16 + c16;
    if (g < 4000) {
      float bb = b2[g];
      float theta = expf(log_theta[g]);
#pragma unroll
      for (int mt = 0; mt < 2; ++mt)
#pragma unroll
        for (int r = 0; r < 4; ++r) {
          int sample = bm * 32 + mt * 16 + lg * 4 + r;
          float s = acc[mt][r] + bb;
          float sig = 1.f / (1.f + expf(-s));
          float mu = (s > 20.f) ? s : log1pf(expf(s));
          float w = theta / (mu * (mu + theta) + 1e-6f);
          Cw[(size_t)sample * 4096 + g] = w * sig * sig;
        }
    } else {
#pragma unroll
      for (int mt = 0; mt < 2; ++mt)
#pragma unroll
        for (int r = 0; r < 4; ++r) {
          int sample = bm * 32 + mt * 16 + lg * 4 + r;
          Cw[(size_t)sample * 4096 + g] = 0.f;
        }
    }
  }
}

// ---------------- main GEMM: 256x256 tile, BK=64, 512 threads, fused Gram epilogue ----------------
// grid (32 M-tiles of 256 rows = 8 samples, 16 N-tiles of 256 genes)
__global__ __launch_bounds__(512, 2) void k_gemm(const unsigned short* __restrict__ Astack,
                                                 const unsigned short* __restrict__ W2T,
                                                 const float* __restrict__ Cw,
                                                 float* __restrict__ Gram) {
  extern __shared__ __align__(16) char smem[];
  char* AbufB = smem;             // 2 * 32768
  char* BbufB = smem + 65536;     // 2 * 32768

  const int bm = blockIdx.x;
  const int g0 = blockIdx.y * 256;
  const int t = threadIdx.x;
  const int lane = t & 63;
  const int wave = t >> 6;           // 0..7
  const int wr = wave >> 2;          // 0..1 : 128-row half
  const int wc = wave & 3;           // 0..3 : 64-col quarter
  const int kxor = (((t & 7) ^ ((t >> 3) & 7)) << 3);
  const int c16 = lane & 15;
  const int lg = lane >> 4;

  f32x4 acc[8][4];
#pragma unroll
  for (int mt = 0; mt < 8; ++mt)
#pragma unroll
    for (int nt = 0; nt < 4; ++nt) acc[mt][nt] = (f32x4){0.f, 0.f, 0.f, 0.f};

  const unsigned short* Aptr = Astack + (size_t)bm * 256 * 512;
  const unsigned short* Bptr = W2T + (size_t)g0 * 512;
  const int trow = t >> 3;           // 0..63

#define STAGE_BIG(buf, kt)                                                            \
  do {                                                                                \
    _Pragma("unroll") for (int q = 0; q < 4; ++q)                                     \
      GLOAD16(Aptr + (size_t)(q * 64 + trow) * 512 + (kt) * 64 + kxor,                \
              AbufB + (buf) * 32768 + q * 8192 + wave * 1024);                        \
    _Pragma("unroll") for (int q = 0; q < 4; ++q)                                     \
      GLOAD16(Bptr + (size_t)(q * 64 + trow) * 512 + (kt) * 64 + kxor,                \
              BbufB + (buf) * 32768 + q * 8192 + wave * 1024);                        \
  } while (0)

  STAGE_BIG(0, 0);
  __syncthreads();

  for (int kt = 0; kt < 8; ++kt) {
    int cur = kt & 1;
    if (kt < 7) STAGE_BIG(cur ^ 1, kt + 1);
    const char* Ab = AbufB + cur * 32768;
    const char* Bb = BbufB + cur * 32768;
#pragma unroll
    for (int ks = 0; ks < 2; ++ks) {
      int kb = ks * 64 + lg * 16;
      bf16x8 av[8], bv[4];
#pragma unroll
      for (int mt = 0; mt < 8; ++mt) {
        int row = wr * 128 + mt * 16 + c16;
        av[mt] = *(const bf16x8*)(Ab + row * 128 + (kb ^ ((row & 7) << 4)));
      }
#pragma unroll
      for (int nt = 0; nt < 4; ++nt) {
        int row = wc * 64 + nt * 16 + c16;
        bv[nt] = *(const bf16x8*)(Bb + row * 128 + (kb ^ ((row & 7) << 4)));
      }
#pragma unroll
      for (int mt = 0; mt < 8; ++mt)
#pragma unroll
        for (int nt = 0; nt < 4; ++nt)
          acc[mt][nt] = __builtin_amdgcn_mfma_f32_16x16x32_bf16(av[mt], bv[nt], acc[mt][nt], 0, 0, 0);
    }
    __syncthreads();
  }

  // ---- epilogue: T tile (bf16, swizzled) -> LDS [256][256], c -> LDS ----
  float* c_lds = (float*)(smem + 131072);   // [8][256]

#pragma unroll
  for (int mt = 0; mt < 8; ++mt)
#pragma unroll
    for (int nt = 0; nt < 4; ++nt)
#pragma unroll
      for (int r = 0; r < 4; ++r) {
        int row = wr * 128 + mt * 16 + lg * 4 + r;
        int col = wc * 64 + nt * 16 + c16;
        *(unsigned short*)(smem + row * 512 + ((col * 2) ^ ((row & 7) << 4))) = f2bf(acc[mt][nt][r]);
      }
#pragma unroll
  for (int k = 0; k < 4; ++k) {
    int e = t + k * 512;
    c_lds[e] = Cw[(size_t)(bm * 8 + (e >> 8)) * 4096 + g0 + (e & 255)];
  }
  __syncthreads();

  // ---- Gram via MFMA: wave s owns sample s; 32x32 over 256 genes ----
  {
    const int s = wave;
    f32x4 gacc[2][2];
#pragma unroll
    for (int m2 = 0; m2 < 2; ++m2)
#pragma unroll
      for (int n2 = 0; n2 < 2; ++n2) gacc[m2][n2] = (f32x4){0.f, 0.f, 0.f, 0.f};

#pragma unroll
    for (int ch = 0; ch < 8; ++ch) {
      f32x4 cv0 = *(const f32x4*)(c_lds + s * 256 + ch * 32 + lg * 8);
      f32x4 cv1 = *(const f32x4*)(c_lds + s * 256 + ch * 32 + lg * 8 + 4);
      u16x8 raw[2];
      bf16x8 ap[2], bp[2];
#pragma unroll
      for (int m2 = 0; m2 < 2; ++m2) {
        int row = s * 32 + m2 * 16 + c16;
        raw[m2] = *(const u16x8*)(smem + row * 512 + ((ch * 64 + lg * 16) ^ ((row & 7) << 4)));
        u16x8 sc;
#pragma unroll
        for (int e = 0; e < 4; ++e) sc[e] = f2bf(bf2f(raw[m2][e]) * cv0[e]);
#pragma unroll
        for (int e = 0; e < 4; ++e) sc[4 + e] = f2bf(bf2f(raw[m2][4 + e]) * cv1[e]);
        ap[m2] = __builtin_bit_cast(bf16x8, sc);
        bp[m2] = __builtin_bit_cast(bf16x8, raw[m2]);
      }
#pragma unroll
      for (int m2 = 0; m2 < 2; ++m2)
#pragma unroll
        for (int n2 = 0; n2 < 2; ++n2)
          gacc[m2][n2] = __builtin_amdgcn_mfma_f32_16x16x32_bf16(ap[m2], bp[n2], gacc[m2][n2], 0, 0, 0);
    }

#pragma unroll
    for (int m2 = 0; m2 < 2; ++m2)
#pragma unroll
      for (int n2 = 0; n2 < 2; ++n2)
#pragma unroll
        for (int r = 0; r < 4; ++r) {
          int i = m2 * 16 + lg * 4 + r;
          int j = n2 * 16 + c16;
          atomicAdd(Gram + (size_t)(bm * 8 + s) * 1024 + i * 32 + j, gacc[m2][n2][r]);
        }
  }
}

// ---------------- loss reduce ----------------
__global__ __launch_bounds__(256) void k_loss(const float* __restrict__ Gram,
                                              float* __restrict__ out) {
  __shared__ float red[4];
  const int b = blockIdx.x, t = threadIdx.x;
  float local = 0.f;
#pragma unroll
  for (int k = 0; k < 4; ++k) {
    int e = t + k * 256;
    float d = Gram[(size_t)b * 1024 + e] - (((e >> 5) == (e & 31)) ? 1.f : 0.f);
    local += d * d;
  }
#pragma unroll
  for (int off = 32; off > 0; off >>= 1) local += __shfl_down(local, off);
  if ((t & 63) == 0) red[t >> 6] = local;
  __syncthreads();
  if (t == 0) {
    float s = red[0] + red[1] + red[2] + red[3];
    atomicAdd(out, s * (1.f / 256.f));
  }
}

extern "C" void kernel_launch(void* const* d_in, const int* in_sizes, int n_in,
                              void* d_out, int out_size, void* d_ws, size_t ws_size,
                              hipStream_t stream) {
  const float* z = (const float*)d_in[0];
  const float* W1 = (const float*)d_in[1];
  const float* b1 = (const float*)d_in[2];
  const float* W2 = (const float*)d_in[3];
  const float* b2 = (const float*)d_in[4];
  const float* lt = (const float*)d_in[5];

  char* ws = (char*)d_ws;
  unsigned short* W2T = (unsigned short*)ws;                   // 4,194,304
  unsigned short* Astack = (unsigned short*)(ws + 4194304);    // 8,388,608
  unsigned short* Hb = (unsigned short*)(ws + 12582912);       // 262,144
  float* Cw = (float*)(ws + 12976128);                         // 4,194,304
  float* Gram = (float*)(ws + 17170432);                       // 1,048,576

  hipMemsetAsync(Gram, 0, 256 * 1024 * 4, stream);
  hipMemsetAsync(d_out, 0, 4, stream);

  static const int kGemmLds = 131072 + 8192;
  hipFuncSetAttribute((const void*)k_gemm, hipFuncAttributeMaxDynamicSharedMemorySize, kGemmLds);

  k_prep2<<<dim3(64, 9), 256, 0, stream>>>(W2, W2T, z, W1, b1, Hb, Astack);
  k_s3<<<dim3(8, 64), 256, 0, stream>>>(Hb, W2T, b2, lt, Cw);
  k_gemm<<<dim3(32, 16), 512, kGemmLds, stream>>>(Astack, W2T, Cw, Gram);
  k_loss<<<256, 256, 0, stream>>>(Gram, (float*)d_out);
}

// Round 8
// 147.502 us; speedup vs baseline: 1.1306x; 1.1306x over previous
//
#include <hip/hip_runtime.h>

typedef __bf16 bf16x8 __attribute__((ext_vector_type(8)));
typedef float f32x4 __attribute__((ext_vector_type(4)));
typedef unsigned short u16x8 __attribute__((ext_vector_type(8)));

typedef const void __attribute__((address_space(1)))* gas_ptr;
typedef void __attribute__((address_space(3)))* las_ptr;

#define GLOAD16(gp, lp) __builtin_amdgcn_global_load_lds((gas_ptr)(gp), (las_ptr)(lp), 16, 0, 0)

__device__ __forceinline__ unsigned short f2bf(float f) {
  unsigned int u = __float_as_uint(f);
  u += 0x7FFF + ((u >> 16) & 1);
  return (unsigned short)(u >> 16);
}
__device__ __forceinline__ float bf2f(unsigned short u) {
  return __uint_as_float(((unsigned int)u) << 16);
}

// ---------------- prep: W2 [512][4000] f32 -> W2T [4096][512] bf16 (zero-padded) ----------------
__global__ __launch_bounds__(256) void k_w2t(const float* __restrict__ W2,
                                             unsigned short* __restrict__ W2T) {
  __shared__ float tile[64][65];
  const int gt = blockIdx.x;
  const int jt = blockIdx.y;
  const int t = threadIdx.x;
  const int c = t & 63, r4 = t >> 6;
#pragma unroll
  for (int r = 0; r < 16; ++r) {
    int jj = r * 4 + r4;
    int g = gt * 64 + c;
    tile[jj][c] = (g < 4000) ? W2[(size_t)(jt * 64 + jj) * 4000 + g] : 0.f;
  }
  __syncthreads();
#pragma unroll
  for (int r = 0; r < 16; ++r) {
    int gg = r * 4 + r4;
    W2T[(size_t)(gt * 64 + gg) * 512 + jt * 64 + c] = f2bf(tile[c][gg]);
  }
}

// ---------------- fused prep: mask + Hb + Astack, one sample per WG ----------------
__global__ __launch_bounds__(256) void k_maskprep(const float* __restrict__ z,
                                                  const float* __restrict__ W1,
                                                  const float* __restrict__ b1,
                                                  unsigned short* __restrict__ Hb,
                                                  unsigned short* __restrict__ Astack) {
  __shared__ float zs[32];
  __shared__ __align__(8) unsigned char mk[512];
  const int b = blockIdx.x, t = threadIdx.x;
  if (t < 32) zs[t] = z[b * 32 + t];
  __syncthreads();
#pragma unroll
  for (int jj = 0; jj < 2; ++jj) {
    int j = t + jj * 256;
    float a = b1[j];
#pragma unroll
    for (int i = 0; i < 32; ++i) a = fmaf(zs[i], W1[i * 512 + j], a);
    bool m = a > 0.f;
    mk[j] = m ? 1 : 0;
    Hb[b * 512 + j] = m ? f2bf(a) : (unsigned short)0;
  }
  __syncthreads();
#pragma unroll
  for (int k = 0; k < 8; ++k) {
    int c8 = t + k * 256;
    int row = c8 >> 6;
    int k8 = (c8 & 63) * 8;
    unsigned long long m8 = *(const unsigned long long*)(mk + k8);
    const float* w = W1 + row * 512 + k8;
    u16x8 out;
#pragma unroll
    for (int e = 0; e < 8; ++e)
      out[e] = ((m8 >> (e * 8)) & 0xffULL) ? f2bf(w[e]) : (unsigned short)0;
    *(u16x8*)(Astack + ((size_t)(b * 32 + row)) * 512 + k8) = out;
  }
}

// ---------------- k_s3: S = H @ W2T^T + b2 -> Cw ----------
__global__ __launch_bounds__(256) void k_s3(const unsigned short* __restrict__ Hb,
                                            const unsigned short* __restrict__ W2T,
                                            const float* __restrict__ b2,
                                            const float* __restrict__ log_theta,
                                            float* __restrict__ Cw) {
  __shared__ __align__(16) char smem[24576];
  char* Abuf = smem;
  char* Bbuf = smem + 8192;

  const int bm = blockIdx.x;
  const int g0 = blockIdx.y * 64;
  const int t = threadIdx.x;
  const int lane = t & 63;
  const int wave = t >> 6;
  const int l8 = lane >> 3;
  const int kxor = (((lane & 7) ^ l8) << 3);
  const int c16 = lane & 15;
  const int lg = lane >> 4;

  f32x4 acc[2];
  acc[0] = (f32x4){0.f, 0.f, 0.f, 0.f};
  acc[1] = (f32x4){0.f, 0.f, 0.f, 0.f};

#define STAGE_S3(buf, kt)                                                             \
  do {                                                                                \
    GLOAD16(Hb + (size_t)(bm * 32 + wave * 8 + l8) * 512 + (kt) * 64 + kxor,          \
            Abuf + (buf) * 4096 + wave * 1024);                                       \
    _Pragma("unroll") for (int qq = 0; qq < 2; ++qq) {                                \
      int q = wave * 2 + qq;                                                          \
      GLOAD16(W2T + (size_t)(g0 + q * 8 + l8) * 512 + (kt) * 64 + kxor,               \
              Bbuf + (buf) * 8192 + q * 1024);                                        \
    }                                                                                 \
  } while (0)

  STAGE_S3(0, 0);
  __syncthreads();

  for (int kt = 0; kt < 8; ++kt) {
    int cur = kt & 1;
    if (kt < 7) STAGE_S3(cur ^ 1, kt + 1);
    const char* Ab = Abuf + cur * 4096;
    const char* Bb = Bbuf + cur * 8192;
#pragma unroll
    for (int ks = 0; ks < 2; ++ks) {
      int kb = ks * 64 + lg * 16;
      bf16x8 av[2], bv;
#pragma unroll
      for (int mt = 0; mt < 2; ++mt) {
        int row = mt * 16 + c16;
        av[mt] = *(const bf16x8*)(Ab + (row >> 3) * 1024 + (row & 7) * 128 + (kb ^ ((row & 7) << 4)));
      }
      {
        int row = wave * 16 + c16;
        bv = *(const bf16x8*)(Bb + (row >> 3) * 1024 + (row & 7) * 128 + (kb ^ ((row & 7) << 4)));
      }
#pragma unroll
      for (int mt = 0; mt < 2; ++mt)
        acc[mt] = __builtin_amdgcn_mfma_f32_16x16x32_bf16(av[mt], bv, acc[mt], 0, 0, 0);
    }
    __syncthreads();
  }

  {
    int g = g0 + wave * 16 + c16;
    if (g < 4000) {
      float bb = b2[g];
      float theta = expf(log_theta[g]);
#pragma unroll
      for (int mt = 0; mt < 2; ++mt)
#pragma unroll
        for (int r = 0; r < 4; ++r) {
          int sample = bm * 32 + mt * 16 + lg * 4 + r;
          float s = acc[mt][r] + bb;
          float sig = 1.f / (1.f + expf(-s));
          float mu = (s > 20.f) ? s : log1pf(expf(s));
          float w = theta / (mu * (mu + theta) + 1e-6f);
          Cw[(size_t)sample * 4096 + g] = w * sig * sig;
        }
    } else {
#pragma unroll
      for (int mt = 0; mt < 2; ++mt)
#pragma unroll
        for (int r = 0; r < 4; ++r) {
          int sample = bm * 32 + mt * 16 + lg * 4 + r;
          Cw[(size_t)sample * 4096 + g] = 0.f;
        }
    }
  }
}

// ---------------- main GEMM: 256x256, BK=64, counted-vmcnt half-tile pipeline ----------------
// grid (32 M-tiles, 16 N-tiles), 512 threads = 8 waves (2M x 4N)
// LDS: buffer b (b=0,1) at smem + b*65536: A[256][64] bf16 swz (+0), B same (+32768)
__global__ __launch_bounds__(512, 2) void k_gemm(const unsigned short* __restrict__ Astack,
                                                 const unsigned short* __restrict__ W2T,
                                                 const float* __restrict__ Cw,
                                                 float* __restrict__ Gram) {
  extern __shared__ __align__(16) char smem[];

  const int bm = blockIdx.x;
  const int g0 = blockIdx.y * 256;
  const int t = threadIdx.x;
  const int lane = t & 63;
  const int wave = t >> 6;
  const int wm = wave >> 2;          // 0..1
  const int wn = wave & 3;           // 0..3
  const int trow = t >> 3;           // 0..63
  const int kxor = (((t & 7) ^ (trow & 7)) << 3);
  const int c16 = lane & 15;
  const int lg = lane >> 4;

  f32x4 acc[8][4];
#pragma unroll
  for (int mt = 0; mt < 8; ++mt)
#pragma unroll
    for (int nt = 0; nt < 4; ++nt) acc[mt][nt] = (f32x4){0.f, 0.f, 0.f, 0.f};

  const unsigned short* Aptr = Astack + (size_t)bm * 256 * 512;
  const unsigned short* Bptr = W2T + (size_t)g0 * 512;

  // stage half h (rows h*128..h*128+127) of K-tile kt into buffer b: 4 loads/thread
#define SHALF(b, kt, h)                                                               \
  do {                                                                                \
    _Pragma("unroll") for (int q = 0; q < 2; ++q) {                                   \
      int row = (h) * 128 + q * 64 + trow;                                            \
      GLOAD16(Aptr + (size_t)row * 512 + (kt) * 64 + kxor,                            \
              smem + (b) * 65536 + row * 128 + (t & 7) * 16);                         \
      GLOAD16(Bptr + (size_t)row * 512 + (kt) * 64 + kxor,                            \
              smem + (b) * 65536 + 32768 + row * 128 + (t & 7) * 16);                 \
    }                                                                                 \
  } while (0)

#define LOAD_BV(cur)                                                                  \
  _Pragma("unroll") for (int nt = 0; nt < 4; ++nt)                                    \
  _Pragma("unroll") for (int ks = 0; ks < 2; ++ks) {                                  \
    int row = wn * 64 + nt * 16 + c16;                                                \
    bv[nt][ks] = *(const bf16x8*)(smem + (cur) * 65536 + 32768 + row * 128 +          \
                                  ((ks * 64 + lg * 16) ^ ((row & 7) << 4)));          \
  }

#define LOAD_AV(cur, mh)                                                              \
  _Pragma("unroll") for (int mi = 0; mi < 4; ++mi)                                    \
  _Pragma("unroll") for (int ks = 0; ks < 2; ++ks) {                                  \
    int row = wm * 128 + ((mh) * 4 + mi) * 16 + c16;                                  \
    av[mi][ks] = *(const bf16x8*)(smem + (cur) * 65536 + row * 128 +                  \
                                  ((ks * 64 + lg * 16) ^ ((row & 7) << 4)));          \
  }

#define MFMA_CLUSTER(mh)                                                              \
  __builtin_amdgcn_s_setprio(1);                                                      \
  _Pragma("unroll") for (int ks = 0; ks < 2; ++ks)                                    \
  _Pragma("unroll") for (int mi = 0; mi < 4; ++mi)                                    \
  _Pragma("unroll") for (int nt = 0; nt < 4; ++nt)                                    \
    acc[(mh) * 4 + mi][nt] =                                                          \
        __builtin_amdgcn_mfma_f32_16x16x32_bf16(av[mi][ks], bv[nt][ks],               \
                                                acc[(mh) * 4 + mi][nt], 0, 0, 0);     \
  __builtin_amdgcn_s_setprio(0);

  // prologue: tile0 both halves, tile1 half0  (12 loads/thread outstanding)
  SHALF(0, 0, 0);
  SHALF(0, 0, 1);
  SHALF(1, 1, 0);

#pragma unroll
  for (int kt = 0; kt < 7; ++kt) {
    const int cur = kt & 1;
    const int nxt = cur ^ 1;
    // tile-kt ready: allow the 4 newest (half0 of kt+1) to stay in flight
    asm volatile("s_waitcnt vmcnt(4)" ::: "memory");
    __builtin_amdgcn_s_barrier();
    __builtin_amdgcn_sched_barrier(0);
    {
      bf16x8 bv[4][2], av[4][2];
      LOAD_BV(cur)
      LOAD_AV(cur, 0)
      MFMA_CLUSTER(0)
      SHALF(nxt, kt + 1, 1);           // half1 of tile kt+1
      LOAD_AV(cur, 1)
      MFMA_CLUSTER(1)
    }
    __builtin_amdgcn_sched_barrier(0);
    __builtin_amdgcn_s_barrier();      // all waves done with tile kt -> cur reusable
    __builtin_amdgcn_sched_barrier(0);
    if (kt < 6) SHALF(cur, kt + 2, 0); // half0 of tile kt+2 into cur
  }
  // peeled last tile (kt=7, buffer 1)
  asm volatile("s_waitcnt vmcnt(0)" ::: "memory");
  __builtin_amdgcn_s_barrier();
  __builtin_amdgcn_sched_barrier(0);
  {
    bf16x8 bv[4][2], av[4][2];
    LOAD_BV(1)
    LOAD_AV(1, 0)
    MFMA_CLUSTER(0)
    LOAD_AV(1, 1)
    MFMA_CLUSTER(1)
  }
  __builtin_amdgcn_sched_barrier(0);
  __builtin_amdgcn_s_barrier();
  __builtin_amdgcn_sched_barrier(0);

  // ---- epilogue: T tile (bf16, swizzled) -> LDS [256][256], c -> LDS ----
  float* c_lds = (float*)(smem + 131072);   // [8][256]

#pragma unroll
  for (int mt = 0; mt < 8; ++mt)
#pragma unroll
    for (int nt = 0; nt < 4; ++nt)
#pragma unroll
      for (int r = 0; r < 4; ++r) {
        int row = wm * 128 + mt * 16 + lg * 4 + r;
        int col = wn * 64 + nt * 16 + c16;
        *(unsigned short*)(smem + row * 512 + ((col * 2) ^ ((row & 7) << 4))) = f2bf(acc[mt][nt][r]);
      }
#pragma unroll
  for (int k = 0; k < 4; ++k) {
    int e = t + k * 512;
    c_lds[e] = Cw[(size_t)(bm * 8 + (e >> 8)) * 4096 + g0 + (e & 255)];
  }
  __syncthreads();

  // ---- Gram via MFMA: wave s owns sample s; 32x32 over 256 genes ----
  {
    const int s = wave;
    f32x4 gacc[2][2];
#pragma unroll
    for (int m2 = 0; m2 < 2; ++m2)
#pragma unroll
      for (int n2 = 0; n2 < 2; ++n2) gacc[m2][n2] = (f32x4){0.f, 0.f, 0.f, 0.f};

#pragma unroll
    for (int ch = 0; ch < 8; ++ch) {
      f32x4 cv0 = *(const f32x4*)(c_lds + s * 256 + ch * 32 + lg * 8);
      f32x4 cv1 = *(const f32x4*)(c_lds + s * 256 + ch * 32 + lg * 8 + 4);
      u16x8 raw[2];
      bf16x8 ap[2], bp[2];
#pragma unroll
      for (int m2 = 0; m2 < 2; ++m2) {
        int row = s * 32 + m2 * 16 + c16;
        raw[m2] = *(const u16x8*)(smem + row * 512 + ((ch * 64 + lg * 16) ^ ((row & 7) << 4)));
        u16x8 sc;
#pragma unroll
        for (int e = 0; e < 4; ++e) sc[e] = f2bf(bf2f(raw[m2][e]) * cv0[e]);
#pragma unroll
        for (int e = 0; e < 4; ++e) sc[4 + e] = f2bf(bf2f(raw[m2][4 + e]) * cv1[e]);
        ap[m2] = __builtin_bit_cast(bf16x8, sc);
        bp[m2] = __builtin_bit_cast(bf16x8, raw[m2]);
      }
#pragma unroll
      for (int m2 = 0; m2 < 2; ++m2)
#pragma unroll
        for (int n2 = 0; n2 < 2; ++n2)
          gacc[m2][n2] = __builtin_amdgcn_mfma_f32_16x16x32_bf16(ap[m2], bp[n2], gacc[m2][n2], 0, 0, 0);
    }

#pragma unroll
    for (int m2 = 0; m2 < 2; ++m2)
#pragma unroll
      for (int n2 = 0; n2 < 2; ++n2)
#pragma unroll
        for (int r = 0; r < 4; ++r) {
          int i = m2 * 16 + lg * 4 + r;
          int j = n2 * 16 + c16;
          atomicAdd(Gram + (size_t)(bm * 8 + s) * 1024 + i * 32 + j, gacc[m2][n2][r]);
        }
  }
}

// ---------------- loss reduce ----------------
__global__ __launch_bounds__(256) void k_loss(const float* __restrict__ Gram,
                                              float* __restrict__ out) {
  __shared__ float red[4];
  const int b = blockIdx.x, t = threadIdx.x;
  float local = 0.f;
#pragma unroll
  for (int k = 0; k < 4; ++k) {
    int e = t + k * 256;
    float d = Gram[(size_t)b * 1024 + e] - (((e >> 5) == (e & 31)) ? 1.f : 0.f);
    local += d * d;
  }
#pragma unroll
  for (int off = 32; off > 0; off >>= 1) local += __shfl_down(local, off);
  if ((t & 63) == 0) red[t >> 6] = local;
  __syncthreads();
  if (t == 0) {
    float s = red[0] + red[1] + red[2] + red[3];
    atomicAdd(out, s * (1.f / 256.f));
  }
}

extern "C" void kernel_launch(void* const* d_in, const int* in_sizes, int n_in,
                              void* d_out, int out_size, void* d_ws, size_t ws_size,
                              hipStream_t stream) {
  const float* z = (const float*)d_in[0];
  const float* W1 = (const float*)d_in[1];
  const float* b1 = (const float*)d_in[2];
  const float* W2 = (const float*)d_in[3];
  const float* b2 = (const float*)d_in[4];
  const float* lt = (const float*)d_in[5];

  char* ws = (char*)d_ws;
  unsigned short* W2T = (unsigned short*)ws;                   // 4,194,304
  unsigned short* Astack = (unsigned short*)(ws + 4194304);    // 8,388,608
  unsigned short* Hb = (unsigned short*)(ws + 12582912);       // 262,144
  float* Cw = (float*)(ws + 12976128);                         // 4,194,304
  float* Gram = (float*)(ws + 17170432);                       // 1,048,576

  hipMemsetAsync(Gram, 0, 256 * 1024 * 4, stream);
  hipMemsetAsync(d_out, 0, 4, stream);

  static const int kGemmLds = 131072 + 8192;
  hipFuncSetAttribute((const void*)k_gemm, hipFuncAttributeMaxDynamicSharedMemorySize, kGemmLds);

  k_w2t<<<dim3(64, 8), 256, 0, stream>>>(W2, W2T);
  k_maskprep<<<256, 256, 0, stream>>>(z, W1, b1, Hb, Astack);
  k_s3<<<dim3(8, 64), 256, 0, stream>>>(Hb, W2T, b2, lt, Cw);
  k_gemm<<<dim3(32, 16), 512, kGemmLds, stream>>>(Astack, W2T, Cw, Gram);
  k_loss<<<256, 256, 0, stream>>>(Gram, (float*)d_out);
}